// Round 5
// baseline (17350.356 us; speedup 1.0000x reference)
//
#include <hip/hip_runtime.h>
#include <math.h>

#define BB 32
#define NN 577
#define DD 384
#define HD 1536
#define LL 12
#define MP 640   // padded mem/key length; multiple of 64 so all GEMM K are %64==0
#define NRPT 4

typedef __attribute__((ext_vector_type(8))) short bf16x8;
typedef __attribute__((ext_vector_type(4))) float f32x4;

__device__ __forceinline__ unsigned short f2bf(float f){
  unsigned u = __builtin_bit_cast(unsigned, f);
  u += 0x7fffu + ((u >> 16) & 1u);
  return (unsigned short)(u >> 16);
}
__device__ __forceinline__ float bf2f(unsigned short s){
  unsigned u = ((unsigned)s) << 16;
  return __builtin_bit_cast(float, u);
}

// async global->LDS, 16B per lane; lds base wave-uniform + lane*16 implicit
__device__ __forceinline__ void async16(void* lds, const void* g){
  __builtin_amdgcn_global_load_lds(
      (const __attribute__((address_space(1))) unsigned int*)g,
      (__attribute__((address_space(3))) unsigned int*)lds, 16, 0, 0);
}

// ---------------- fused repeat-prep ----------------
// r>=1: mem rows 1..NN-1 and the zero tail are unchanged -> skip their writes.
__global__ void prep_k(float* __restrict__ x, const float* __restrict__ xp,
                       float* __restrict__ cls_r, const float* __restrict__ cls_hist,
                       unsigned short* __restrict__ mem, int r){
  int i = blockIdx.x * 256 + threadIdx.x;
  if (i >= BB*MP*DD) return;
  int d = i % DD;
  int n = (i / DD) % MP;
  int b = i / (MP*DD);
  float v; bool wr = true;
  if (n == 0){ v = x[(size_t)b*NN*DD + d]; cls_r[b*DD + d] = v; }
  else if (n < NN){ v = xp[((size_t)b*NN + n)*DD + d]; x[((size_t)b*NN + n)*DD + d] = v; wr = (r==0); }
  else if (n < NN + r){ v = cls_hist[(size_t)(n-NN)*BB*DD + b*DD + d]; wr = (n == NN + r - 1); }
  else { v = 0.f; wr = (r==0); }
  if (wr) mem[i] = f2bf(v);
}

// cast ALL layers' weights once (hoisted out of the repeat/layer loops)
__global__ void cast_all_k(const float* __restrict__ qkvw, const float* __restrict__ pw,
                           const float* __restrict__ f1w, const float* __restrict__ f2w,
                           unsigned short* __restrict__ wbuf){
  int i = blockIdx.x * 256 + threadIdx.x;
  const int QKV = 3*DD*DD;
  const int PRJ = DD*DD;
  const int F1  = HD*DD;
  const int TOT = QKV + PRJ + 2*F1;
  if (i >= LL*TOT) return;
  int l = i / TOT, j = i % TOT;
  float v;
  if (j < QKV) v = qkvw[(size_t)l*QKV + j];
  else if (j < QKV+PRJ) v = pw[(size_t)l*PRJ + (j-QKV)];
  else if (j < QKV+PRJ+F1) v = f1w[(size_t)l*F1 + (j-QKV-PRJ)];
  else v = f2w[(size_t)l*F1 + (j-QKV-PRJ-F1)];
  wbuf[i] = f2bf(v);
}

// ---------------- LayerNorm: 4 rows per block, vectorized loads ----------------
template<typename T>
__global__ __launch_bounds__(256) void ln4_k(const T* __restrict__ in, const float* __restrict__ w,
                                             const float* __restrict__ bias, unsigned short* __restrict__ out,
                                             int nrows){
  int row = blockIdx.x*4 + (threadIdx.x >> 6);
  if (row >= nrows) return;
  int lane = threadIdx.x & 63;
  const T* p = in + (size_t)row*DD;
  float v[6];
  if constexpr (sizeof(T) == 4){
    const float* pf = (const float*)p;
    float4 a = *(const float4*)(pf + lane*4);
    float2 c = *(const float2*)(pf + 256 + lane*2);
    v[0]=a.x; v[1]=a.y; v[2]=a.z; v[3]=a.w; v[4]=c.x; v[5]=c.y;
  } else {
    const unsigned short* ps = (const unsigned short*)p;
    ushort4 a = *(const ushort4*)(ps + lane*4);
    ushort2 c = *(const ushort2*)(ps + 256 + lane*2);
    v[0]=bf2f(a.x); v[1]=bf2f(a.y); v[2]=bf2f(a.z); v[3]=bf2f(a.w);
    v[4]=bf2f(c.x); v[5]=bf2f(c.y);
  }
  float s = v[0]+v[1]+v[2]+v[3]+v[4]+v[5];
  #pragma unroll
  for (int o=32;o;o>>=1) s += __shfl_xor(s, o, 64);
  float mu = s * (1.f/DD);
  float q = 0.f;
  #pragma unroll
  for (int i=0;i<6;i++){ float t = v[i]-mu; q += t*t; }
  #pragma unroll
  for (int o=32;o;o>>=1) q += __shfl_xor(q, o, 64);
  float rs = rsqrtf(q*(1.f/DD) + 1e-6f);
  float4 w4 = *(const float4*)(w + lane*4);
  float2 w2 = *(const float2*)(w + 256 + lane*2);
  float4 b4 = *(const float4*)(bias + lane*4);
  float2 b2 = *(const float2*)(bias + 256 + lane*2);
  unsigned short* po = out + (size_t)row*DD;
  ushort4 o4;
  o4.x = f2bf((v[0]-mu)*rs*w4.x + b4.x);
  o4.y = f2bf((v[1]-mu)*rs*w4.y + b4.y);
  o4.z = f2bf((v[2]-mu)*rs*w4.z + b4.z);
  o4.w = f2bf((v[3]-mu)*rs*w4.w + b4.w);
  *(ushort4*)(po + lane*4) = o4;
  ushort2 o2;
  o2.x = f2bf((v[4]-mu)*rs*w2.x + b2.x);
  o2.y = f2bf((v[5]-mu)*rs*w2.y + b2.y);
  *(ushort2*)(po + 256 + lane*2) = o2;
}

// ---------------- k/v cache fixup: recompute 2 changed mem rows per repeat ----------------
// task per wave: (b, rsel, kind). kind 0 = k row (GEMV + LN), kind 1 = v row (GEMV -> vT col).
__global__ __launch_bounds__(256) void fixup_k(
    const unsigned short* __restrict__ mem,
    const unsigned short* __restrict__ wq,      // layer qkv weights (Wk at +DD*DD, Wv at +2*DD*DD)
    const float* __restrict__ qkvb,             // layer bias base (k at +DD, v at +2*DD)
    const float* __restrict__ knw, const float* __restrict__ knb,
    unsigned short* __restrict__ kc,            // [BB*MP][DD]
    unsigned short* __restrict__ vc,            // [BB][DD][MP]
    int row2){
  int task = blockIdx.x*4 + (threadIdx.x >> 6);   // 128 tasks
  int lane = threadIdx.x & 63;
  int kind = task & 1;
  int rsel = (task >> 1) & 1;
  int b    = task >> 2;
  int row  = rsel ? row2 : 0;
  const unsigned short* mrow = mem + ((size_t)b*MP + row)*DD;
  const unsigned short* W = wq + (size_t)(kind+1)*DD*DD;
  const float* bias = qkvb + (kind+1)*DD;

  float acc[6] = {0,0,0,0,0,0};
  for (int i=0;i<48;i++){
    bf16x8 m8 = *(const bf16x8*)(mrow + i*8);
    float mf[8];
    #pragma unroll
    for (int j=0;j<8;j++) mf[j] = bf2f((unsigned short)m8[j]);
    #pragma unroll
    for (int c=0;c<6;c++){
      bf16x8 w8 = *(const bf16x8*)(W + (size_t)(lane + c*64)*DD + i*8);
      #pragma unroll
      for (int j=0;j<8;j++) acc[c] += mf[j]*bf2f((unsigned short)w8[j]);
    }
  }
  #pragma unroll
  for (int c=0;c<6;c++) acc[c] += bias[lane + c*64];

  if (kind == 0){
    float s1 = 0.f, s2 = 0.f;
    #pragma unroll
    for (int c=0;c<6;c++){ s1 += acc[c]; s2 += acc[c]*acc[c]; }
    #pragma unroll
    for (int o=32;o;o>>=1){ s1 += __shfl_xor(s1, o, 64); s2 += __shfl_xor(s2, o, 64); }
    float mu = s1*(1.f/DD);
    float var = s2*(1.f/DD) - mu*mu;
    float rs = rsqrtf(fmaxf(var, 0.f) + 1e-6f);
    unsigned short* out = kc + ((size_t)b*MP + row)*DD;
    #pragma unroll
    for (int c=0;c<6;c++){
      int col = lane + c*64;
      out[col] = f2bf((acc[c]-mu)*rs*knw[col] + knb[col]);
    }
  } else {
    #pragma unroll
    for (int c=0;c<6;c++){
      int d = lane + c*64;
      vc[((size_t)b*DD + d)*MP + row] = f2bf(acc[c]);
    }
  }
}

// ---------------- 128x128 GEMM, BK=64 double-buffered, counted-vmcnt pipeline ----------------
// T3/T4-minimum 2-phase: issue next tile's global_load_lds BEFORE computing the
// current tile; end each K-step with asm vmcnt(0) + RAW s_barrier (loads overlap
// compute; __syncthreads would drain them at issue time).
template<int EPI>
__global__ __launch_bounds__(256, 2) void gemm128(
    const unsigned short* __restrict__ A, int lda, int arows, long sA,
    const unsigned short* __restrict__ B, int ldb, int brows, long sB,
    const float* __restrict__ bias,
    int K, int N,
    float* __restrict__ outF, unsigned short* __restrict__ outB,
    int ldo, int orows, long sO,
    const float* __restrict__ ls){

  __shared__ unsigned short a_sh[2][2][128*32];   // [buf][khalf][row*32+k]
  __shared__ unsigned short b_sh[2][2][128*32];

  int tid  = threadIdx.x;
  int wave = tid >> 6, lane = tid & 63;
  int lr = lane & 15, kg = lane >> 4;
  int wm = wave >> 1, wn = wave & 1;
  int z = blockIdx.z;
  int row0 = blockIdx.y * 128;
  int col0 = blockIdx.x * 128;

  const unsigned short* Ab = A + (size_t)z*sA;
  const unsigned short* Bb = B + (size_t)z*sB;

  f32x4 zf = {0.f,0.f,0.f,0.f};
  f32x4 acc[4][4];
  #pragma unroll
  for (int i=0;i<4;i++)
    #pragma unroll
    for (int j=0;j<4;j++) acc[i][j] = zf;

  int ra[2], rb[2], kc[2];
  #pragma unroll
  for (int it=0; it<2; it++){
    int c = tid + it*256;
    int r = row0 + (c>>2); if (r > arows-1) r = arows-1;
    ra[it] = r;
    r = col0 + (c>>2); if (r > brows-1) r = brows-1;
    rb[it] = r;
    kc[it] = (c&3)*8;
  }

  auto stage = [&](int buf, int k0){
    #pragma unroll
    for (int p=0;p<2;p++){
      #pragma unroll
      for (int it=0; it<2; it++){
        async16(&a_sh[buf][p][(it*256 + wave*64)*8], Ab + (size_t)ra[it]*lda + k0 + p*32 + kc[it]);
        async16(&b_sh[buf][p][(it*256 + wave*64)*8], Bb + (size_t)rb[it]*ldb + k0 + p*32 + kc[it]);
      }
    }
  };

  int nt = K >> 6;
  stage(0, 0);
  asm volatile("s_waitcnt vmcnt(0)" ::: "memory");
  __builtin_amdgcn_s_barrier();

  for (int t=0; t<nt; t++){
    int cur = t & 1;
    if (t+1 < nt) stage(cur^1, (t+1)*64);   // prefetch flies under the MFMAs below
    __builtin_amdgcn_s_setprio(1);
    #pragma unroll
    for (int p=0;p<2;p++){
      bf16x8 af[4], bfr[4];
      #pragma unroll
      for (int i=0;i<4;i++){
        af[i]  = *(const bf16x8*)&a_sh[cur][p][(wm*64 + i*16 + lr)*32 + kg*8];
        bfr[i] = *(const bf16x8*)&b_sh[cur][p][(wn*64 + i*16 + lr)*32 + kg*8];
      }
      #pragma unroll
      for (int i=0;i<4;i++)
        #pragma unroll
        for (int j=0;j<4;j++)
          acc[i][j] = __builtin_amdgcn_mfma_f32_16x16x32_bf16(af[i], bfr[j], acc[i][j], 0,0,0);
    }
    __builtin_amdgcn_s_setprio(0);
    // wait for the prefetched tile to land in LDS, then release all waves.
    asm volatile("s_waitcnt vmcnt(0)" ::: "memory");
    __builtin_amdgcn_s_barrier();
  }

  float* oF = outF ? outF + (size_t)z*sO : nullptr;
  unsigned short* oB = outB ? outB + (size_t)z*sO : nullptr;

  #pragma unroll
  for (int mi=0;mi<4;mi++)
    #pragma unroll
    for (int ni=0;ni<4;ni++)
      #pragma unroll
      for (int r=0;r<4;r++){
        int row = row0 + wm*64 + mi*16 + kg*4 + r;
        int col = col0 + wn*64 + ni*16 + lr;
        if (row >= orows || col >= N) continue;
        float vv = acc[mi][ni][r];
        size_t idx = (size_t)row*ldo + col;
        if (EPI == 0){
          if (bias) vv += bias[col];
          oB[idx] = f2bf(vv);
        } else if (EPI == 1){
          vv += bias[row];
          oB[idx] = f2bf(vv);
        } else if (EPI == 2){
          vv += bias[col];
          oF[idx] = vv*ls[col] + oF[idx];
        } else {
          vv += bias[col];
          float g = 0.5f*vv*(1.f + erff(vv*0.70710678118f));
          oB[idx] = f2bf(g);
        }
      }
}

// ---------------- fused flash attention + q-LN + an-LayerNorm ----------------
// qraw: [B*NN][384] raw q (bias applied); q-LN (qn) + 1/sqrt(D) fused in-kernel.
// kb: [B*MP][384] LN'd k; vT: [B][384][MP]. out = LN_an(softmax(qk)@v) bf16.
__global__ __launch_bounds__(256, 2) void attn_k(
    const unsigned short* __restrict__ qraw,
    const float* __restrict__ qw, const float* __restrict__ qb_,
    const unsigned short* __restrict__ kb,
    const unsigned short* __restrict__ vT,
    const float* __restrict__ anw, const float* __restrict__ anb,
    unsigned short* __restrict__ out, int M){

  __shared__ unsigned short k_sh[32*384];   // swizzled: LDS[row][c'] = g[row][c' low3^row&7]
  __shared__ unsigned short v_sh[384*32];   // swizzled: LDS[d][c'] = g[d][c'^ (d&3)]
  __shared__ unsigned short p_sh[64*56];    // P in A-layout, padded stride 56

  int tid = threadIdx.x;
  int wv = tid >> 6, lane = tid & 63;
  int lr = lane & 15, kg = lane >> 4;
  int b = blockIdx.y, qt0 = blockIdx.x * 64;

  // q A-frags in registers with fused LN(qn_w,qn_b) and softmax scale.
  bf16x8 qf[12];
  {
    int qrow = qt0 + wv*16 + lr; if (qrow > NN-1) qrow = NN-1;
    const unsigned short* qp = qraw + ((size_t)b*NN + qrow)*DD;
    float s1 = 0.f, s2 = 0.f;
    #pragma unroll
    for (int ks=0; ks<12; ks++){
      qf[ks] = *(const bf16x8*)(qp + ks*32 + kg*8);
      #pragma unroll
      for (int j=0;j<8;j++){
        float t = bf2f((unsigned short)qf[ks][j]);
        s1 += t; s2 += t*t;
      }
    }
    s1 += __shfl_xor(s1, 16, 64); s1 += __shfl_xor(s1, 32, 64);
    s2 += __shfl_xor(s2, 16, 64); s2 += __shfl_xor(s2, 32, 64);
    const float SC = 0.05103103588f;   // 1/sqrt(384), folded into LN
    float mu = s1 * (1.f/DD);
    float var = s2 * (1.f/DD) - mu*mu;
    float rs = rsqrtf(fmaxf(var, 0.f) + 1e-6f) * SC;
    #pragma unroll
    for (int ks=0; ks<12; ks++){
      int c0 = ks*32 + kg*8;
      float4 wa = *(const float4*)(qw + c0);
      float4 wb = *(const float4*)(qw + c0 + 4);
      float4 ba = *(const float4*)(qb_ + c0);
      float4 bb = *(const float4*)(qb_ + c0 + 4);
      bf16x8 t;
      t[0] = (short)f2bf((bf2f((unsigned short)qf[ks][0])-mu)*rs*wa.x + ba.x*SC);
      t[1] = (short)f2bf((bf2f((unsigned short)qf[ks][1])-mu)*rs*wa.y + ba.y*SC);
      t[2] = (short)f2bf((bf2f((unsigned short)qf[ks][2])-mu)*rs*wa.z + ba.z*SC);
      t[3] = (short)f2bf((bf2f((unsigned short)qf[ks][3])-mu)*rs*wa.w + ba.w*SC);
      t[4] = (short)f2bf((bf2f((unsigned short)qf[ks][4])-mu)*rs*wb.x + bb.x*SC);
      t[5] = (short)f2bf((bf2f((unsigned short)qf[ks][5])-mu)*rs*wb.y + bb.y*SC);
      t[6] = (short)f2bf((bf2f((unsigned short)qf[ks][6])-mu)*rs*wb.z + bb.z*SC);
      t[7] = (short)f2bf((bf2f((unsigned short)qf[ks][7])-mu)*rs*wb.w + bb.w*SC);
      qf[ks] = t;
    }
  }

  f32x4 zf = {0.f,0.f,0.f,0.f};
  f32x4 O[24];
  #pragma unroll
  for (int i=0;i<24;i++) O[i] = zf;
  float m_run[4], l_run[4];
  #pragma unroll
  for (int r=0;r<4;r++){ m_run[r] = -INFINITY; l_run[r] = 0.f; }

  for (int kt=0; kt<19; kt++){
    __syncthreads();   // protect LDS from previous iteration's readers
    // stage k-tile: 32 rows x 48 chunks
    #pragma unroll
    for (int i=0;i<6;i++){
      int L = i*256 + tid;
      int row = L/48, c = L%48;
      int gc = (c & ~7) | ((c ^ row) & 7);
      async16(&k_sh[L*8], kb + ((size_t)b*MP + kt*32 + row)*DD + gc*8);
    }
    // stage v-tile: 384 d-rows x 4 chunks
    #pragma unroll
    for (int i=0;i<6;i++){
      int L = i*256 + tid;
      int row = L>>2;
      int gc = (L&3) ^ (row&3);
      async16(&v_sh[L*8], vT + ((size_t)b*DD + row)*MP + kt*32 + gc*8);
    }
    __syncthreads();   // staged data visible

    // QK: wave computes rows wv*16..+15 x 32 keys (2 col tiles)
    f32x4 s[2] = {zf, zf};
    __builtin_amdgcn_s_setprio(1);
    #pragma unroll
    for (int ks=0; ks<12; ks++){
      int c = ks*4 + kg;
      #pragma unroll
      for (int nk=0; nk<2; nk++){
        int krow = nk*16 + lr;
        bf16x8 bk = *(const bf16x8*)&k_sh[krow*DD + ((c & ~7) | ((c ^ krow)&7))*8];
        s[nk] = __builtin_amdgcn_mfma_f32_16x16x32_bf16(qf[ks], bk, s[nk], 0,0,0);
      }
    }
    __builtin_amdgcn_s_setprio(0);
    // mask cols >= M (per-lane uniform per nk)
    #pragma unroll
    for (int nk=0; nk<2; nk++){
      if (kt*32 + nk*16 + lr >= M){
        s[nk][0] = -INFINITY; s[nk][1] = -INFINITY; s[nk][2] = -INFINITY; s[nk][3] = -INFINITY;
      }
    }
    // tile max per row (rows kg*4+r, local to wave)
    float vmax[4];
    #pragma unroll
    for (int r=0;r<4;r++){
      float v = fmaxf(s[0][r], s[1][r]);
      v = fmaxf(v, __shfl_xor(v, 1, 64));
      v = fmaxf(v, __shfl_xor(v, 2, 64));
      v = fmaxf(v, __shfl_xor(v, 4, 64));
      v = fmaxf(v, __shfl_xor(v, 8, 64));
      vmax[r] = v;
    }
    // T13 defer-max: skip rescale when max didn't grow past THR=8.
    bool small = (vmax[0] <= m_run[0] + 8.f) & (vmax[1] <= m_run[1] + 8.f)
               & (vmax[2] <= m_run[2] + 8.f) & (vmax[3] <= m_run[3] + 8.f);
    if (!__all(small)){
      #pragma unroll
      for (int r=0;r<4;r++){
        float mn = fmaxf(m_run[r], vmax[r]);
        float al = __expf(m_run[r] - mn);
        m_run[r] = mn;
        l_run[r] *= al;
        #pragma unroll
        for (int ni=0;ni<24;ni++) O[ni][r] *= al;
      }
    }
    #pragma unroll
    for (int nk=0;nk<2;nk++)
      #pragma unroll
      for (int r=0;r<4;r++)
        s[nk][r] = __expf(s[nk][r] - m_run[r]);
    #pragma unroll
    for (int r=0;r<4;r++){
      float v = s[0][r] + s[1][r];
      v += __shfl_xor(v, 1, 64);
      v += __shfl_xor(v, 2, 64);
      v += __shfl_xor(v, 4, 64);
      v += __shfl_xor(v, 8, 64);
      l_run[r] += v;
    }
    // write P (C-layout lanes) to p_sh in A-layout rows
    #pragma unroll
    for (int nk=0;nk<2;nk++)
      #pragma unroll
      for (int r=0;r<4;r++)
        p_sh[(wv*16 + kg*4 + r)*56 + nk*16 + lr] = f2bf(s[nk][r]);
    __syncthreads();   // p_sh visible (cross-lane)

    // PV: A = p rows wv*16+lr (k = 32 keys, one MFMA k-step), B = v_sh
    bf16x8 ap = *(const bf16x8*)&p_sh[(wv*16 + lr)*56 + kg*8];
    __builtin_amdgcn_s_setprio(1);
    #pragma unroll
    for (int ni=0;ni<24;ni++){
      int d = ni*16 + lr;
      bf16x8 bv = *(const bf16x8*)&v_sh[d*32 + ((kg ^ (d&3))*8)];
      O[ni] = __builtin_amdgcn_mfma_f32_16x16x32_bf16(ap, bv, O[ni], 0,0,0);
    }
    __builtin_amdgcn_s_setprio(0);
  }

  // epilogue: normalize by l, then LN(an) — fully wave-local (row split)
  float inv[4];
  #pragma unroll
  for (int r=0;r<4;r++) inv[r] = 1.f / l_run[r];
  float s1[4] = {0,0,0,0}, s2[4] = {0,0,0,0};
  #pragma unroll
  for (int ni=0;ni<24;ni++)
    #pragma unroll
    for (int r=0;r<4;r++){
      float x = O[ni][r]*inv[r];
      O[ni][r] = x;
      s1[r] += x; s2[r] += x*x;
    }
  #pragma unroll
  for (int r=0;r<4;r++){
    #pragma unroll
    for (int o=1;o<16;o<<=1){ s1[r] += __shfl_xor(s1[r], o, 64); s2[r] += __shfl_xor(s2[r], o, 64); }
  }
  float mu[4], rs[4];
  #pragma unroll
  for (int r=0;r<4;r++){
    mu[r] = s1[r]*(1.f/DD);
    float var = s2[r]*(1.f/DD) - mu[r]*mu[r];
    rs[r] = rsqrtf(fmaxf(var, 0.f) + 1e-6f);
  }
  int rowb = qt0 + wv*16 + kg*4;
  #pragma unroll
  for (int ni=0;ni<24;ni++){
    int col = ni*16 + lr;
    float wc = anw[col], bc = anb[col];
    #pragma unroll
    for (int r=0;r<4;r++){
      int qrow = rowb + r;
      if (qrow < NN)
        out[((size_t)b*NN + qrow)*DD + col] = f2bf((O[ni][r]-mu[r])*rs[r]*wc + bc);
    }
  }
}

// ---------------- launcher ----------------

extern "C" void kernel_launch(void* const* d_in, const int* in_sizes, int n_in,
                              void* d_out, int out_size, void* d_ws, size_t ws_size,
                              hipStream_t stream){
  const float* x_in = (const float*)d_in[0];
  const float* n1w  = (const float*)d_in[1];
  const float* n1b  = (const float*)d_in[2];
  const float* qkvw = (const float*)d_in[3];
  const float* qkvb = (const float*)d_in[4];
  const float* qnw  = (const float*)d_in[5];
  const float* qnb  = (const float*)d_in[6];
  const float* knw  = (const float*)d_in[7];
  const float* knb  = (const float*)d_in[8];
  const float* anw  = (const float*)d_in[9];
  const float* anb  = (const float*)d_in[10];
  const float* pw   = (const float*)d_in[11];
  const float* pb   = (const float*)d_in[12];
  const float* ls1  = (const float*)d_in[13];
  const float* n2w  = (const float*)d_in[14];
  const float* n2b  = (const float*)d_in[15];
  const float* f1w  = (const float*)d_in[16];
  const float* f1b  = (const float*)d_in[17];
  const float* f2w  = (const float*)d_in[18];
  const float* f2bb = (const float*)d_in[19];
  const float* ls2  = (const float*)d_in[20];

  const int QKV = 3*DD*DD, PRJ = DD*DD, F1 = HD*DD;
  const size_t WTOT = (size_t)QKV + PRJ + 2*F1;
  const size_t SLOT = (size_t)BB*MP*DD;      // elems in one k/v/activation slot

  auto aln = [](size_t v){ return (v + 255) & ~(size_t)255; };
  const size_t WB = aln(LL*WTOT*2);              // 42.5 MB weights (bf16, all layers)
  const size_t CH = aln((size_t)NRPT*BB*DD*4);   // cls history (f32)
  const size_t MB_ = aln(SLOT*2);                // mem bf16
  const size_t SL = aln(SLOT*2);                 // one 384-wide activation slot
  const size_t HB = aln((size_t)BB*NN*HD*2);     // fc1 output (1536-wide), 56.7 MB
  const size_t CPL = 2*SL;                       // per-layer k+v cache

  char* ws = (char*)d_ws;
  size_t off = 0;
  auto take = [&](size_t bytes)->char* { char* p = ws + off; off += bytes; return p; };

  unsigned short* wbuf   = (unsigned short*)take(WB);
  float*          cls_h  = (float*)         take(CH);
  unsigned short* mem_bf = (unsigned short*)take(MB_);
  unsigned short* S0     = (unsigned short*)take(SL);   // xn / prodn / x2
  unsigned short* HQ     = (unsigned short*)take(HB);   // qraw (head) / h (full)

  // adaptive k/v caching: cache as many layers as fit in the remaining workspace
  int nc;
  unsigned short *kscr = nullptr, *vscr = nullptr, *kcache = nullptr, *vcache = nullptr;
  if (off + (size_t)LL*CPL <= ws_size){
    nc = LL;
    kcache = (unsigned short*)take((size_t)LL*SL);
    vcache = (unsigned short*)take((size_t)LL*SL);
  } else {
    kscr = (unsigned short*)take(SL);
    vscr = (unsigned short*)take(SL);
    size_t avail = (ws_size > off) ? ws_size - off : 0;
    nc = (int)(avail / CPL); if (nc > LL) nc = LL; if (nc < 0) nc = 0;
    kcache = (unsigned short*)take((size_t)nc*SL);
    vcache = (unsigned short*)take((size_t)nc*SL);
  }

  unsigned short* xn    = S0;
  unsigned short* qraw  = HQ;
  unsigned short* prodn = S0;
  unsigned short* x2    = S0;
  unsigned short* h     = HQ;

  float* xf = (float*)d_out;

  auto cg = [](size_t n){ return dim3((unsigned)((n + 255) / 256)); };

  hipMemcpyAsync(xf, x_in, (size_t)BB*NN*DD*4, hipMemcpyDeviceToDevice, stream);

  const int RT  = (BB*NN + 127)/128;
  const int RTM = (BB*MP)/128;
  const int QR  = BB*NN;
  const int KR  = BB*MP;

  // one-time weight cast for all layers
  cast_all_k<<<cg((size_t)LL*WTOT),256,0,stream>>>(qkvw, pw, f1w, f2w, wbuf);

  for (int r = 0; r < NRPT; r++){
    int M = NN + r;
    prep_k<<<cg((size_t)BB*MP*DD),256,0,stream>>>(xf, x_in, cls_h + (size_t)r*BB*DD, cls_h, mem_bf, r);
    for (int l = 0; l < LL; l++){
      const unsigned short* wl = wbuf + (size_t)l*WTOT;
      const unsigned short* wq = wl;
      const unsigned short* wp = wl + QKV;
      const unsigned short* w1 = wl + QKV + PRJ;
      const unsigned short* w2 = wl + QKV + PRJ + F1;

      bool cached = (l < nc);
      unsigned short* kbuf = cached ? kcache + (size_t)l*SLOT : kscr;
      unsigned short* vbuf = cached ? vcache + (size_t)l*SLOT : vscr;

      ln4_k<float><<<cg((size_t)QR*64),256,0,stream>>>(xf, n1w + l*DD, n1b + l*DD, xn, QR);
      gemm128<0><<<dim3(3,RT,1),256,0,stream>>>(xn,384,QR,0, wq,384,384,0,
          qkvb + l*3*DD, 384,384, nullptr,qraw,384,QR,0, nullptr);

      if (!cached || r == 0){
        // full k GEMM + in-place k-LN, full vT GEMM (repeat 0 fills the caches)
        gemm128<0><<<dim3(3,RTM,1),256,0,stream>>>(mem_bf,384,KR,0, wq + (size_t)DD*DD,384,384,0,
            qkvb + l*3*DD + DD, 384,384, nullptr,kbuf,384,KR,0, nullptr);
        gemm128<1><<<dim3(MP/128,3,BB),256,0,stream>>>(wq + (size_t)2*DD*DD,384,384,0, mem_bf,384,MP,(long)MP*DD,
            qkvb + l*3*DD + 2*DD, 384,MP, nullptr,vbuf,MP,384,(long)DD*MP, nullptr);
        ln4_k<unsigned short><<<cg((size_t)KR*64),256,0,stream>>>(kbuf, knw + l*DD, knb + l*DD, kbuf, KR);
      } else {
        // only mem rows {0, NN+r-1} changed since the cache was filled
        fixup_k<<<32,256,0,stream>>>(mem_bf, wq, qkvb + l*3*DD,
                                     knw + l*DD, knb + l*DD, kbuf, vbuf, NN + r - 1);
      }

      attn_k<<<dim3(10,BB),256,0,stream>>>(qraw, qnw + l*DD, qnb + l*DD, kbuf, vbuf,
                                           anw + l*DD, anb + l*DD, prodn, M);
      gemm128<2><<<dim3(3,RT,1),256,0,stream>>>(prodn,384,QR,0, wp,384,384,0,
          pb + l*DD, 384,384, xf,nullptr,384,QR,0, ls1 + l*DD);
      ln4_k<float><<<cg((size_t)QR*64),256,0,stream>>>(xf, n2w + l*DD, n2b + l*DD, x2, QR);
      gemm128<3><<<dim3(HD/128,RT,1),256,0,stream>>>(x2,384,QR,0, w1,384,HD,0,
          f1b + l*HD, 384,HD, nullptr,h,HD,QR,0, nullptr);
      gemm128<2><<<dim3(3,RT,1),256,0,stream>>>(h,HD,QR,0, w2,HD,384,0,
          f2bb + l*DD, HD,384, xf,nullptr,384,QR,0, ls2 + l*DD);
    }
  }
}

// Round 6
// 15618.004 us; speedup vs baseline: 1.1109x; 1.1109x over previous
//
#include <hip/hip_runtime.h>
#include <math.h>

#define BB 32
#define NN 577
#define DD 384
#define HD 1536
#define LL 12
#define MP 640   // padded mem/key length; multiple of 64 so all GEMM K are %64==0
#define NRPT 4

typedef __attribute__((ext_vector_type(8))) short bf16x8;
typedef __attribute__((ext_vector_type(4))) float f32x4;

__device__ __forceinline__ unsigned short f2bf(float f){
  unsigned u = __builtin_bit_cast(unsigned, f);
  u += 0x7fffu + ((u >> 16) & 1u);
  return (unsigned short)(u >> 16);
}
__device__ __forceinline__ float bf2f(unsigned short s){
  unsigned u = ((unsigned)s) << 16;
  return __builtin_bit_cast(float, u);
}

// async global->LDS, 16B per lane; lds base wave-uniform + lane*16 implicit
__device__ __forceinline__ void async16(void* lds, const void* g){
  __builtin_amdgcn_global_load_lds(
      (const __attribute__((address_space(1))) unsigned int*)g,
      (__attribute__((address_space(3))) unsigned int*)lds, 16, 0, 0);
}

// ---------------- fused repeat-prep ----------------
// r>=1: mem rows 1..NN-1 and the zero tail are unchanged -> skip their writes.
__global__ void prep_k(float* __restrict__ x, const float* __restrict__ xp,
                       float* __restrict__ cls_r, const float* __restrict__ cls_hist,
                       unsigned short* __restrict__ mem, int r){
  int i = blockIdx.x * 256 + threadIdx.x;
  if (i >= BB*MP*DD) return;
  int d = i % DD;
  int n = (i / DD) % MP;
  int b = i / (MP*DD);
  float v; bool wr = true;
  if (n == 0){ v = x[(size_t)b*NN*DD + d]; cls_r[b*DD + d] = v; }
  else if (n < NN){ v = xp[((size_t)b*NN + n)*DD + d]; x[((size_t)b*NN + n)*DD + d] = v; wr = (r==0); }
  else if (n < NN + r){ v = cls_hist[(size_t)(n-NN)*BB*DD + b*DD + d]; wr = (n == NN + r - 1); }
  else { v = 0.f; wr = (r==0); }
  if (wr) mem[i] = f2bf(v);
}

// cast ALL layers' weights once (hoisted out of the repeat/layer loops)
__global__ void cast_all_k(const float* __restrict__ qkvw, const float* __restrict__ pw,
                           const float* __restrict__ f1w, const float* __restrict__ f2w,
                           unsigned short* __restrict__ wbuf){
  int i = blockIdx.x * 256 + threadIdx.x;
  const int QKV = 3*DD*DD;
  const int PRJ = DD*DD;
  const int F1  = HD*DD;
  const int TOT = QKV + PRJ + 2*F1;
  if (i >= LL*TOT) return;
  int l = i / TOT, j = i % TOT;
  float v;
  if (j < QKV) v = qkvw[(size_t)l*QKV + j];
  else if (j < QKV+PRJ) v = pw[(size_t)l*PRJ + (j-QKV)];
  else if (j < QKV+PRJ+F1) v = f1w[(size_t)l*F1 + (j-QKV-PRJ)];
  else v = f2w[(size_t)l*F1 + (j-QKV-PRJ-F1)];
  wbuf[i] = f2bf(v);
}

// ---------------- LayerNorm: 4 rows per block, vectorized loads ----------------
template<typename T>
__global__ __launch_bounds__(256) void ln4_k(const T* __restrict__ in, const float* __restrict__ w,
                                             const float* __restrict__ bias, unsigned short* __restrict__ out,
                                             int nrows){
  int row = blockIdx.x*4 + (threadIdx.x >> 6);
  if (row >= nrows) return;
  int lane = threadIdx.x & 63;
  const T* p = in + (size_t)row*DD;
  float v[6];
  if constexpr (sizeof(T) == 4){
    const float* pf = (const float*)p;
    float4 a = *(const float4*)(pf + lane*4);
    float2 c = *(const float2*)(pf + 256 + lane*2);
    v[0]=a.x; v[1]=a.y; v[2]=a.z; v[3]=a.w; v[4]=c.x; v[5]=c.y;
  } else {
    const unsigned short* ps = (const unsigned short*)p;
    ushort4 a = *(const ushort4*)(ps + lane*4);
    ushort2 c = *(const ushort2*)(ps + 256 + lane*2);
    v[0]=bf2f(a.x); v[1]=bf2f(a.y); v[2]=bf2f(a.z); v[3]=bf2f(a.w);
    v[4]=bf2f(c.x); v[5]=bf2f(c.y);
  }
  float s = v[0]+v[1]+v[2]+v[3]+v[4]+v[5];
  #pragma unroll
  for (int o=32;o;o>>=1) s += __shfl_xor(s, o, 64);
  float mu = s * (1.f/DD);
  float q = 0.f;
  #pragma unroll
  for (int i=0;i<6;i++){ float t = v[i]-mu; q += t*t; }
  #pragma unroll
  for (int o=32;o;o>>=1) q += __shfl_xor(q, o, 64);
  float rs = rsqrtf(q*(1.f/DD) + 1e-6f);
  float4 w4 = *(const float4*)(w + lane*4);
  float2 w2 = *(const float2*)(w + 256 + lane*2);
  float4 b4 = *(const float4*)(bias + lane*4);
  float2 b2 = *(const float2*)(bias + 256 + lane*2);
  unsigned short* po = out + (size_t)row*DD;
  ushort4 o4;
  o4.x = f2bf((v[0]-mu)*rs*w4.x + b4.x);
  o4.y = f2bf((v[1]-mu)*rs*w4.y + b4.y);
  o4.z = f2bf((v[2]-mu)*rs*w4.z + b4.z);
  o4.w = f2bf((v[3]-mu)*rs*w4.w + b4.w);
  *(ushort4*)(po + lane*4) = o4;
  ushort2 o2;
  o2.x = f2bf((v[4]-mu)*rs*w2.x + b2.x);
  o2.y = f2bf((v[5]-mu)*rs*w2.y + b2.y);
  *(ushort2*)(po + 256 + lane*2) = o2;
}

// ---------------- k/v cache fixup: recompute 2 changed mem rows per repeat ----------------
__global__ __launch_bounds__(256) void fixup_k(
    const unsigned short* __restrict__ mem,
    const unsigned short* __restrict__ wq,
    const float* __restrict__ qkvb,
    const float* __restrict__ knw, const float* __restrict__ knb,
    unsigned short* __restrict__ kc,            // [BB*MP][DD]
    unsigned short* __restrict__ vc,            // [BB][DD][MP]
    int row2){
  int task = blockIdx.x*4 + (threadIdx.x >> 6);   // 128 tasks
  int lane = threadIdx.x & 63;
  int kind = task & 1;
  int rsel = (task >> 1) & 1;
  int b    = task >> 2;
  int row  = rsel ? row2 : 0;
  const unsigned short* mrow = mem + ((size_t)b*MP + row)*DD;
  const unsigned short* W = wq + (size_t)(kind+1)*DD*DD;
  const float* bias = qkvb + (kind+1)*DD;

  float acc[6] = {0,0,0,0,0,0};
  for (int i=0;i<48;i++){
    bf16x8 m8 = *(const bf16x8*)(mrow + i*8);
    float mf[8];
    #pragma unroll
    for (int j=0;j<8;j++) mf[j] = bf2f((unsigned short)m8[j]);
    #pragma unroll
    for (int c=0;c<6;c++){
      bf16x8 w8 = *(const bf16x8*)(W + (size_t)(lane + c*64)*DD + i*8);
      #pragma unroll
      for (int j=0;j<8;j++) acc[c] += mf[j]*bf2f((unsigned short)w8[j]);
    }
  }
  #pragma unroll
  for (int c=0;c<6;c++) acc[c] += bias[lane + c*64];

  if (kind == 0){
    float s1 = 0.f, s2 = 0.f;
    #pragma unroll
    for (int c=0;c<6;c++){ s1 += acc[c]; s2 += acc[c]*acc[c]; }
    #pragma unroll
    for (int o=32;o;o>>=1){ s1 += __shfl_xor(s1, o, 64); s2 += __shfl_xor(s2, o, 64); }
    float mu = s1*(1.f/DD);
    float var = s2*(1.f/DD) - mu*mu;
    float rs = rsqrtf(fmaxf(var, 0.f) + 1e-6f);
    unsigned short* out = kc + ((size_t)b*MP + row)*DD;
    #pragma unroll
    for (int c=0;c<6;c++){
      int col = lane + c*64;
      out[col] = f2bf((acc[c]-mu)*rs*knw[col] + knb[col]);
    }
  } else {
    #pragma unroll
    for (int c=0;c<6;c++){
      int d = lane + c*64;
      vc[((size_t)b*DD + d)*MP + row] = f2bf(acc[c]);
    }
  }
}

// ---------------- shared 128x128 GEMM body (BK=64, serial staging — R3-proven) ----------------
__device__ __forceinline__ void gemm_body(
    unsigned short (*a_sh)[128*32], unsigned short (*b_sh)[128*32],
    const unsigned short* __restrict__ Ab, int lda, int arows,
    const unsigned short* __restrict__ Bb, int ldb, int brows,
    const float* __restrict__ bias, int K, int N,
    unsigned short* __restrict__ oB, int ldo, int orows,
    int epi, int row0, int col0){

  int tid  = threadIdx.x;
  int wave = tid >> 6, lane = tid & 63;
  int lr = lane & 15, kg = lane >> 4;
  int wm = wave >> 1, wn = wave & 1;

  f32x4 zf = {0.f,0.f,0.f,0.f};
  f32x4 acc[4][4];
  #pragma unroll
  for (int i=0;i<4;i++)
    #pragma unroll
    for (int j=0;j<4;j++) acc[i][j] = zf;

  int ra[2], rb[2], kc[2];
  #pragma unroll
  for (int it=0; it<2; it++){
    int c = tid + it*256;
    int r = row0 + (c>>2); if (r > arows-1) r = arows-1;
    ra[it] = r;
    r = col0 + (c>>2); if (r > brows-1) r = brows-1;
    rb[it] = r;
    kc[it] = (c&3)*8;
  }

  for (int k0 = 0; k0 < K; k0 += 64){
    #pragma unroll
    for (int p=0;p<2;p++){
      #pragma unroll
      for (int it=0; it<2; it++){
        async16(&a_sh[p][(it*256 + wave*64)*8], Ab + (size_t)ra[it]*lda + k0 + p*32 + kc[it]);
        async16(&b_sh[p][(it*256 + wave*64)*8], Bb + (size_t)rb[it]*ldb + k0 + p*32 + kc[it]);
      }
    }
    __syncthreads();
    #pragma unroll
    for (int p=0;p<2;p++){
      bf16x8 af[4], bfr[4];
      #pragma unroll
      for (int i=0;i<4;i++){
        af[i]  = *(const bf16x8*)&a_sh[p][(wm*64 + i*16 + lr)*32 + kg*8];
        bfr[i] = *(const bf16x8*)&b_sh[p][(wn*64 + i*16 + lr)*32 + kg*8];
      }
      #pragma unroll
      for (int i=0;i<4;i++)
        #pragma unroll
        for (int j=0;j<4;j++)
          acc[i][j] = __builtin_amdgcn_mfma_f32_16x16x32_bf16(af[i], bfr[j], acc[i][j], 0,0,0);
    }
    __syncthreads();
  }

  #pragma unroll
  for (int mi=0;mi<4;mi++)
    #pragma unroll
    for (int ni=0;ni<4;ni++)
      #pragma unroll
      for (int r=0;r<4;r++){
        int row = row0 + wm*64 + mi*16 + kg*4 + r;
        int col = col0 + wn*64 + ni*16 + lr;
        if (row >= orows || col >= N) continue;
        float vv = acc[mi][ni][r];
        vv += (epi == 0) ? bias[col] : bias[row];
        oB[(size_t)row*ldo + col] = f2bf(vv);
      }
}

// ---------------- merged q+k+v GEMM dispatch (one launch, 3 independent GEMMs) ----------------
// blocks [0,435): q = xn@Wq^T   (3 col x 145 row tiles)
// blocks [435,915): k = mem@Wk^T (3 x 160)
// blocks [915,1395): vT[z] = Wv@mem[z]^T (per-batch 5 col x 3 row, z=0..31)
__global__ __launch_bounds__(256) void gemmqkv_k(
    const unsigned short* __restrict__ xn, const unsigned short* __restrict__ mem,
    const unsigned short* __restrict__ wq, const float* __restrict__ qkvb,
    unsigned short* __restrict__ qout, unsigned short* __restrict__ kout,
    unsigned short* __restrict__ vout, int QR){

  __shared__ unsigned short a_sh[2][128*32];
  __shared__ unsigned short b_sh[2][128*32];

  int bid = blockIdx.x;
  const unsigned short *A, *B;
  const float* bias;
  unsigned short* out;
  int arows, brows, N, ldo, orows, epi, row0, col0;

  if (bid < 435){
    int gx = bid % 3, gy = bid / 3;
    A = xn; arows = QR; B = wq; brows = 384;
    bias = qkvb; N = 384; out = qout; ldo = 384; orows = QR; epi = 0;
    row0 = gy*128; col0 = gx*128;
  } else if (bid < 915){
    int t = bid - 435; int gx = t % 3, gy = t / 3;
    A = mem; arows = BB*MP; B = wq + DD*DD; brows = 384;
    bias = qkvb + DD; N = 384; out = kout; ldo = 384; orows = BB*MP; epi = 0;
    row0 = gy*128; col0 = gx*128;
  } else {
    int t = bid - 915; int z = t/15; int rem = t%15; int gx = rem % 5, gy = rem / 5;
    A = wq + 2*DD*DD; arows = 384;
    B = mem + (size_t)z*MP*DD; brows = MP;
    bias = qkvb + 2*DD; N = MP; out = vout + (size_t)z*DD*MP; ldo = MP; orows = 384; epi = 1;
    row0 = gy*128; col0 = gx*128;
  }
  gemm_body(a_sh, b_sh, A, 384, arows, B, 384, brows, bias, 384, N, out, ldo, orows, epi, row0, col0);
}

// ---------------- 128x128 LDS-staged GEMM, BK=64 (proj / fc1 / fc2 / cached-q) ----------------
template<int EPI>
__global__ __launch_bounds__(256) void gemm128(
    const unsigned short* __restrict__ A, int lda, int arows, long sA,
    const unsigned short* __restrict__ B, int ldb, int brows, long sB,
    const float* __restrict__ bias,
    int K, int N,
    float* __restrict__ outF, unsigned short* __restrict__ outB,
    int ldo, int orows, long sO,
    const float* __restrict__ ls){

  __shared__ unsigned short a_sh[2][128*32];
  __shared__ unsigned short b_sh[2][128*32];

  int tid  = threadIdx.x;
  int wave = tid >> 6, lane = tid & 63;
  int lr = lane & 15, kg = lane >> 4;
  int wm = wave >> 1, wn = wave & 1;
  int z = blockIdx.z;
  int row0 = blockIdx.y * 128;
  int col0 = blockIdx.x * 128;

  const unsigned short* Ab = A + (size_t)z*sA;
  const unsigned short* Bb = B + (size_t)z*sB;

  f32x4 zf = {0.f,0.f,0.f,0.f};
  f32x4 acc[4][4];
  #pragma unroll
  for (int i=0;i<4;i++)
    #pragma unroll
    for (int j=0;j<4;j++) acc[i][j] = zf;

  int ra[2], rb[2], kc[2];
  #pragma unroll
  for (int it=0; it<2; it++){
    int c = tid + it*256;
    int r = row0 + (c>>2); if (r > arows-1) r = arows-1;
    ra[it] = r;
    r = col0 + (c>>2); if (r > brows-1) r = brows-1;
    rb[it] = r;
    kc[it] = (c&3)*8;
  }

  for (int k0 = 0; k0 < K; k0 += 64){
    #pragma unroll
    for (int p=0;p<2;p++){
      #pragma unroll
      for (int it=0; it<2; it++){
        unsigned short* la = &a_sh[p][(it*256 + wave*64)*8];
        unsigned short* lb = &b_sh[p][(it*256 + wave*64)*8];
        async16(la, Ab + (size_t)ra[it]*lda + k0 + p*32 + kc[it]);
        async16(lb, Bb + (size_t)rb[it]*ldb + k0 + p*32 + kc[it]);
      }
    }
    __syncthreads();
    #pragma unroll
    for (int p=0;p<2;p++){
      bf16x8 af[4], bfr[4];
      #pragma unroll
      for (int i=0;i<4;i++){
        af[i]  = *(const bf16x8*)&a_sh[p][(wm*64 + i*16 + lr)*32 + kg*8];
        bfr[i] = *(const bf16x8*)&b_sh[p][(wn*64 + i*16 + lr)*32 + kg*8];
      }
      #pragma unroll
      for (int i=0;i<4;i++)
        #pragma unroll
        for (int j=0;j<4;j++)
          acc[i][j] = __builtin_amdgcn_mfma_f32_16x16x32_bf16(af[i], bfr[j], acc[i][j], 0,0,0);
    }
    __syncthreads();
  }

  float* oF = outF ? outF + (size_t)z*sO : nullptr;
  unsigned short* oB = outB ? outB + (size_t)z*sO : nullptr;

  #pragma unroll
  for (int mi=0;mi<4;mi++)
    #pragma unroll
    for (int ni=0;ni<4;ni++)
      #pragma unroll
      for (int r=0;r<4;r++){
        int row = row0 + wm*64 + mi*16 + kg*4 + r;
        int col = col0 + wn*64 + ni*16 + lr;
        if (row >= orows || col >= N) continue;
        float vv = acc[mi][ni][r];
        size_t idx = (size_t)row*ldo + col;
        if (EPI == 0){
          if (bias) vv += bias[col];
          oB[idx] = f2bf(vv);
        } else if (EPI == 1){
          vv += bias[row];
          oB[idx] = f2bf(vv);
        } else if (EPI == 2){
          vv += bias[col];
          oF[idx] = vv*ls[col] + oF[idx];
        } else {
          vv += bias[col];
          float g = 0.5f*vv*(1.f + erff(vv*0.70710678118f));
          oB[idx] = f2bf(g);
        }
      }
}

// ---------------- fused flash attention + q-LN + an-LayerNorm ----------------
__global__ __launch_bounds__(256, 2) void attn_k(
    const unsigned short* __restrict__ qraw,
    const float* __restrict__ qw, const float* __restrict__ qb_,
    const unsigned short* __restrict__ kb,
    const unsigned short* __restrict__ vT,
    const float* __restrict__ anw, const float* __restrict__ anb,
    unsigned short* __restrict__ out, int M){

  __shared__ unsigned short k_sh[32*384];   // swizzled: LDS[row][c'] = g[row][c' low3^row&7]
  __shared__ unsigned short v_sh[384*32];   // swizzled: LDS[d][c'] = g[d][c'^ (d&3)]
  __shared__ unsigned short p_sh[64*56];    // P in A-layout, padded stride 56

  int tid = threadIdx.x;
  int wv = tid >> 6, lane = tid & 63;
  int lr = lane & 15, kg = lane >> 4;
  int b = blockIdx.y, qt0 = blockIdx.x * 64;

  // q A-frags in registers with fused LN(qn_w,qn_b) and softmax scale.
  bf16x8 qf[12];
  {
    int qrow = qt0 + wv*16 + lr; if (qrow > NN-1) qrow = NN-1;
    const unsigned short* qp = qraw + ((size_t)b*NN + qrow)*DD;
    float s1 = 0.f, s2 = 0.f;
    #pragma unroll
    for (int ks=0; ks<12; ks++){
      qf[ks] = *(const bf16x8*)(qp + ks*32 + kg*8);
      #pragma unroll
      for (int j=0;j<8;j++){
        float t = bf2f((unsigned short)qf[ks][j]);
        s1 += t; s2 += t*t;
      }
    }
    s1 += __shfl_xor(s1, 16, 64); s1 += __shfl_xor(s1, 32, 64);
    s2 += __shfl_xor(s2, 16, 64); s2 += __shfl_xor(s2, 32, 64);
    const float SC = 0.05103103588f;   // 1/sqrt(384), folded into LN
    float mu = s1 * (1.f/DD);
    float var = s2 * (1.f/DD) - mu*mu;
    float rs = rsqrtf(fmaxf(var, 0.f) + 1e-6f) * SC;
    #pragma unroll
    for (int ks=0; ks<12; ks++){
      int c0 = ks*32 + kg*8;
      float4 wa = *(const float4*)(qw + c0);
      float4 wb = *(const float4*)(qw + c0 + 4);
      float4 ba = *(const float4*)(qb_ + c0);
      float4 bb = *(const float4*)(qb_ + c0 + 4);
      bf16x8 t;
      t[0] = (short)f2bf((bf2f((unsigned short)qf[ks][0])-mu)*rs*wa.x + ba.x*SC);
      t[1] = (short)f2bf((bf2f((unsigned short)qf[ks][1])-mu)*rs*wa.y + ba.y*SC);
      t[2] = (short)f2bf((bf2f((unsigned short)qf[ks][2])-mu)*rs*wa.z + ba.z*SC);
      t[3] = (short)f2bf((bf2f((unsigned short)qf[ks][3])-mu)*rs*wa.w + ba.w*SC);
      t[4] = (short)f2bf((bf2f((unsigned short)qf[ks][4])-mu)*rs*wb.x + bb.x*SC);
      t[5] = (short)f2bf((bf2f((unsigned short)qf[ks][5])-mu)*rs*wb.y + bb.y*SC);
      t[6] = (short)f2bf((bf2f((unsigned short)qf[ks][6])-mu)*rs*wb.z + bb.z*SC);
      t[7] = (short)f2bf((bf2f((unsigned short)qf[ks][7])-mu)*rs*wb.w + bb.w*SC);
      qf[ks] = t;
    }
  }

  f32x4 zf = {0.f,0.f,0.f,0.f};
  f32x4 O[24];
  #pragma unroll
  for (int i=0;i<24;i++) O[i] = zf;
  float m_run[4], l_run[4];
  #pragma unroll
  for (int r=0;r<4;r++){ m_run[r] = -INFINITY; l_run[r] = 0.f; }

  for (int kt=0; kt<19; kt++){
    __syncthreads();   // protect LDS from previous iteration's readers
    // stage k-tile: 32 rows x 48 chunks
    #pragma unroll
    for (int i=0;i<6;i++){
      int L = i*256 + tid;
      int row = L/48, c = L%48;
      int gc = (c & ~7) | ((c ^ row) & 7);
      async16(&k_sh[L*8], kb + ((size_t)b*MP + kt*32 + row)*DD + gc*8);
    }
    // stage v-tile: 384 d-rows x 4 chunks
    #pragma unroll
    for (int i=0;i<6;i++){
      int L = i*256 + tid;
      int row = L>>2;
      int gc = (L&3) ^ (row&3);
      async16(&v_sh[L*8], vT + ((size_t)b*DD + row)*MP + kt*32 + gc*8);
    }
    __syncthreads();   // staged data visible

    // QK: wave computes rows wv*16..+15 x 32 keys (2 col tiles)
    f32x4 s[2] = {zf, zf};
    __builtin_amdgcn_s_setprio(1);
    #pragma unroll
    for (int ks=0; ks<12; ks++){
      int c = ks*4 + kg;
      #pragma unroll
      for (int nk=0; nk<2; nk++){
        int krow = nk*16 + lr;
        bf16x8 bk = *(const bf16x8*)&k_sh[krow*DD + ((c & ~7) | ((c ^ krow)&7))*8];
        s[nk] = __builtin_amdgcn_mfma_f32_16x16x32_bf16(qf[ks], bk, s[nk], 0,0,0);
      }
    }
    __builtin_amdgcn_s_setprio(0);
    // mask cols >= M (per-lane uniform per nk)
    #pragma unroll
    for (int nk=0; nk<2; nk++){
      if (kt*32 + nk*16 + lr >= M){
        s[nk][0] = -INFINITY; s[nk][1] = -INFINITY; s[nk][2] = -INFINITY; s[nk][3] = -INFINITY;
      }
    }
    // tile max per row (rows kg*4+r, local to wave)
    float vmax[4];
    #pragma unroll
    for (int r=0;r<4;r++){
      float v = fmaxf(s[0][r], s[1][r]);
      v = fmaxf(v, __shfl_xor(v, 1, 64));
      v = fmaxf(v, __shfl_xor(v, 2, 64));
      v = fmaxf(v, __shfl_xor(v, 4, 64));
      v = fmaxf(v, __shfl_xor(v, 8, 64));
      vmax[r] = v;
    }
    // T13 defer-max: skip rescale when max didn't grow past THR=8.
    bool small = (vmax[0] <= m_run[0] + 8.f) & (vmax[1] <= m_run[1] + 8.f)
               & (vmax[2] <= m_run[2] + 8.f) & (vmax[3] <= m_run[3] + 8.f);
    if (!__all(small)){
      #pragma unroll
      for (int r=0;r<4;r++){
        float mn = fmaxf(m_run[r], vmax[r]);
        float al = __expf(m_run[r] - mn);
        m_run[r] = mn;
        l_run[r] *= al;
        #pragma unroll
        for (int ni=0;ni<24;ni++) O[ni][r] *= al;
      }
    }
    #pragma unroll
    for (int nk=0;nk<2;nk++)
      #pragma unroll
      for (int r=0;r<4;r++)
        s[nk][r] = __expf(s[nk][r] - m_run[r]);
    #pragma unroll
    for (int r=0;r<4;r++){
      float v = s[0][r] + s[1][r];
      v += __shfl_xor(v, 1, 64);
      v += __shfl_xor(v, 2, 64);
      v += __shfl_xor(v, 4, 64);
      v += __shfl_xor(v, 8, 64);
      l_run[r] += v;
    }
    // write P (C-layout lanes) to p_sh in A-layout rows
    #pragma unroll
    for (int nk=0;nk<2;nk++)
      #pragma unroll
      for (int r=0;r<4;r++)
        p_sh[(wv*16 + kg*4 + r)*56 + nk*16 + lr] = f2bf(s[nk][r]);
    __syncthreads();   // p_sh visible (cross-lane)

    // PV: A = p rows wv*16+lr (k = 32 keys, one MFMA k-step), B = v_sh
    bf16x8 ap = *(const bf16x8*)&p_sh[(wv*16 + lr)*56 + kg*8];
    __builtin_amdgcn_s_setprio(1);
    #pragma unroll
    for (int ni=0;ni<24;ni++){
      int d = ni*16 + lr;
      bf16x8 bv = *(const bf16x8*)&v_sh[d*32 + ((kg ^ (d&3))*8)];
      O[ni] = __builtin_amdgcn_mfma_f32_16x16x32_bf16(ap, bv, O[ni], 0,0,0);
    }
    __builtin_amdgcn_s_setprio(0);
  }

  // epilogue: normalize by l, then LN(an) — fully wave-local (row split)
  float inv[4];
  #pragma unroll
  for (int r=0;r<4;r++) inv[r] = 1.f / l_run[r];
  float s1[4] = {0,0,0,0}, s2[4] = {0,0,0,0};
  #pragma unroll
  for (int ni=0;ni<24;ni++)
    #pragma unroll
    for (int r=0;r<4;r++){
      float x = O[ni][r]*inv[r];
      O[ni][r] = x;
      s1[r] += x; s2[r] += x*x;
    }
  #pragma unroll
  for (int r=0;r<4;r++){
    #pragma unroll
    for (int o=1;o<16;o<<=1){ s1[r] += __shfl_xor(s1[r], o, 64); s2[r] += __shfl_xor(s2[r], o, 64); }
  }
  float mu[4], rs[4];
  #pragma unroll
  for (int r=0;r<4;r++){
    mu[r] = s1[r]*(1.f/DD);
    float var = s2[r]*(1.f/DD) - mu[r]*mu[r];
    rs[r] = rsqrtf(fmaxf(var, 0.f) + 1e-6f);
  }
  int rowb = qt0 + wv*16 + kg*4;
  #pragma unroll
  for (int ni=0;ni<24;ni++){
    int col = ni*16 + lr;
    float wc = anw[col], bc = anb[col];
    #pragma unroll
    for (int r=0;r<4;r++){
      int qrow = rowb + r;
      if (qrow < NN)
        out[((size_t)b*NN + qrow)*DD + col] = f2bf((O[ni][r]-mu[r])*rs[r]*wc + bc);
    }
  }
}

// ---------------- launcher ----------------

extern "C" void kernel_launch(void* const* d_in, const int* in_sizes, int n_in,
                              void* d_out, int out_size, void* d_ws, size_t ws_size,
                              hipStream_t stream){
  const float* x_in = (const float*)d_in[0];
  const float* n1w  = (const float*)d_in[1];
  const float* n1b  = (const float*)d_in[2];
  const float* qkvw = (const float*)d_in[3];
  const float* qkvb = (const float*)d_in[4];
  const float* qnw  = (const float*)d_in[5];
  const float* qnb  = (const float*)d_in[6];
  const float* knw  = (const float*)d_in[7];
  const float* knb  = (const float*)d_in[8];
  const float* anw  = (const float*)d_in[9];
  const float* anb  = (const float*)d_in[10];
  const float* pw   = (const float*)d_in[11];
  const float* pb   = (const float*)d_in[12];
  const float* ls1  = (const float*)d_in[13];
  const float* n2w  = (const float*)d_in[14];
  const float* n2b  = (const float*)d_in[15];
  const float* f1w  = (const float*)d_in[16];
  const float* f1b  = (const float*)d_in[17];
  const float* f2w  = (const float*)d_in[18];
  const float* f2bb = (const float*)d_in[19];
  const float* ls2  = (const float*)d_in[20];

  char* ws = (char*)d_ws;
  size_t off = 0;
  auto alloc = [&](size_t bytes)->char* {
    char* p = ws + off;
    off = (off + bytes + 255) & ~(size_t)255;
    return p;
  };

  const int QKV = 3*DD*DD, PRJ = DD*DD, F1 = HD*DD;
  const size_t WTOT = (size_t)QKV + PRJ + 2*F1;
  const size_t SLOT = (size_t)BB*MP*DD;

  unsigned short* wbuf  = (unsigned short*)alloc((size_t)LL*WTOT*2);  // all 12 layers
  float*          cls_h = (float*)         alloc((size_t)NRPT*BB*DD*4);
  unsigned short* mem_bf= (unsigned short*)alloc(SLOT*2);
  unsigned short* pool  = (unsigned short*)alloc(6*SLOT*2);
  // per-layer k/v caches (persist across repeats); guarded by ws_size
  unsigned short* kcache = (unsigned short*)alloc((size_t)LL*SLOT*2);
  unsigned short* vcache = (unsigned short*)alloc((size_t)LL*SLOT*2);
  bool use_cache = (off <= ws_size);

  unsigned short* S0 = pool;
  unsigned short* S1 = pool + SLOT;
  unsigned short* S2 = pool + 2*SLOT;
  unsigned short* S3 = pool + 3*SLOT;
  unsigned short* S5 = pool + 5*SLOT;

  unsigned short* xn    = S0;   // ln1 out
  unsigned short* qraw  = S1;   // q gemm out (attn does q-LN internally)
  unsigned short* prodn = S3;   // attn out
  unsigned short* x2    = S0;   // ln2 out
  unsigned short* h     = S1;   // fc1 out, spans S1..S4

  float* xf = (float*)d_out;

  auto cg = [](size_t n){ return dim3((unsigned)((n + 255) / 256)); };

  hipMemcpyAsync(xf, x_in, (size_t)BB*NN*DD*4, hipMemcpyDeviceToDevice, stream);

  const int RT  = (BB*NN + 127)/128;
  const int QR  = BB*NN;
  const int KR  = BB*MP;

  // one-time weight cast for all layers
  cast_all_k<<<cg((size_t)LL*WTOT),256,0,stream>>>(qkvw, pw, f1w, f2w, wbuf);

  for (int r = 0; r < NRPT; r++){
    int M = NN + r;
    prep_k<<<cg((size_t)BB*MP*DD),256,0,stream>>>(xf, x_in, cls_h + (size_t)r*BB*DD, cls_h, mem_bf, r);
    for (int l = 0; l < LL; l++){
      const unsigned short* wl = wbuf + (size_t)l*WTOT;
      const unsigned short* wq = wl;
      const unsigned short* wp = wl + QKV;
      const unsigned short* w1 = wl + QKV + PRJ;
      const unsigned short* w2 = wl + QKV + PRJ + F1;

      bool cached = use_cache;
      unsigned short* kbuf = cached ? kcache + (size_t)l*SLOT : S2;
      unsigned short* vbuf = cached ? vcache + (size_t)l*SLOT : S5;

      ln4_k<float><<<cg((size_t)QR*64),256,0,stream>>>(xf, n1w + l*DD, n1b + l*DD, xn, QR);

      if (!cached || r == 0){
        // ONE dispatch for all three independent GEMMs (q, k, vT)
        gemmqkv_k<<<1395,256,0,stream>>>(xn, mem_bf, wq, qkvb + l*3*DD, qraw, kbuf, vbuf, QR);
        ln4_k<unsigned short><<<cg((size_t)KR*64),256,0,stream>>>(kbuf, knw + l*DD, knb + l*DD, kbuf, KR);
      } else {
        gemm128<0><<<dim3(3,RT,1),256,0,stream>>>(xn,384,QR,0, wq,384,384,0,
            qkvb + l*3*DD, 384,384, nullptr,qraw,384,QR,0, nullptr);
        // only mem rows {0, NN+r-1} changed since the cache was filled
        fixup_k<<<32,256,0,stream>>>(mem_bf, wq, qkvb + l*3*DD,
                                     knw + l*DD, knb + l*DD, kbuf, vbuf, NN + r - 1);
      }

      attn_k<<<dim3(10,BB),256,0,stream>>>(qraw, qnw + l*DD, qnb + l*DD, kbuf, vbuf,
                                           anw + l*DD, anb + l*DD, prodn, M);
      gemm128<2><<<dim3(3,RT,1),256,0,stream>>>(prodn,384,QR,0, wp,384,384,0,
          pb + l*DD, 384,384, xf,nullptr,384,QR,0, ls1 + l*DD);
      ln4_k<float><<<cg((size_t)QR*64),256,0,stream>>>(xf, n2w + l*DD, n2b + l*DD, x2, QR);
      gemm128<3><<<dim3(HD/128,RT,1),256,0,stream>>>(x2,384,QR,0, w1,384,HD,0,
          f1b + l*HD, 384,HD, nullptr,h,HD,QR,0, nullptr);
      gemm128<2><<<dim3(3,RT,1),256,0,stream>>>(h,HD,QR,0, w2,HD,384,0,
          f2bb + l*DD, HD,384, xf,nullptr,384,QR,0, ls2 + l*DD);
    }
  }
}